// Round 1
// baseline (315.217 us; speedup 1.0000x reference)
//
#include <hip/hip_runtime.h>
#include <hip/hip_bf16.h>

#define BATCH 64
#define CDIM  256
#define MHW   196
#define MP    224      // padded K for covariance (multiple of 32)
#define EDIM  512
#define CC    65536    // CDIM*CDIM

typedef __attribute__((ext_vector_type(8))) short short8_t;   // 8 x bf16 MFMA frag
typedef __attribute__((ext_vector_type(4))) float f32x4;
typedef __attribute__((ext_vector_type(4))) unsigned int u32x4;

static __device__ __forceinline__ short f2bf(float f) {
    __hip_bfloat16 h = __float2bfloat16(f);
    return (short)__builtin_bit_cast(unsigned short, h);
}

// ---------------------------------------------------------------------------
// Kernel 1: per-(b,c) row centering, bf16 cast (padded to MP), trace accum
// tr[b] = sum of squares of centered rows = trace(xc @ xc^T)
// ---------------------------------------------------------------------------
__global__ __launch_bounds__(256) void k_center(const float* __restrict__ feat,
                                                __hip_bfloat16* __restrict__ xcb,
                                                float* __restrict__ tr)
{
    const int row = blockIdx.x * 4 + (threadIdx.x >> 6);   // [0, 64*256)
    const int l = threadIdx.x & 63;
    const int b = row >> 8;
    const float* src = feat + (size_t)row * MHW;
    float v0 = src[l];
    float v1 = src[l + 64];
    float v2 = src[l + 128];
    float v3 = (l + 192 < MHW) ? src[l + 192] : 0.0f;
    float s = v0 + v1 + v2 + v3;
    #pragma unroll
    for (int o = 32; o >= 1; o >>= 1) s += __shfl_xor(s, o, 64);
    const float mean = s * (1.0f / MHW);
    v0 -= mean; v1 -= mean; v2 -= mean;
    v3 = (l + 192 < MHW) ? (v3 - mean) : 0.0f;
    float sq = v0*v0 + v1*v1 + v2*v2 + v3*v3;
    #pragma unroll
    for (int o = 32; o >= 1; o >>= 1) sq += __shfl_xor(sq, o, 64);
    if (l == 0) atomicAdd(tr + b, sq);
    __hip_bfloat16* dst = xcb + (size_t)row * MP;
    dst[l]       = __float2bfloat16(v0);
    dst[l + 64]  = __float2bfloat16(v1);
    dst[l + 128] = __float2bfloat16(v2);
    if (l + 192 < MP) dst[l + 192] = __float2bfloat16(v3);   // includes zero pad
}

// ---------------------------------------------------------------------------
// Kernel 2: batched symmetric matmul tile kernel.
// out = a*(A@B) + beta*D + gamma*I   per batch, 256x256, bf16 in/out, f32 acc.
// a = alpha_c * (alpha_ptr ? (recip ? 1/alpha_ptr[b] : alpha_ptr[b]) : 1)
// B is read via its ROWS (valid: every B operand is exactly symmetric in
// storage thanks to mirrored writes). Upper-triangle tiles only (t=0,1,2 ->
// (0,0),(0,1),(1,1)); off-diagonal tile mirror-writes.
// KT: K extent AND row stride of A/B (224 for covariance input, else 256).
// ---------------------------------------------------------------------------
template<int KT, bool NORM>
__global__ __launch_bounds__(256) void k_mm(const __hip_bfloat16* __restrict__ A,
                                            const __hip_bfloat16* __restrict__ Bm,
                                            const __hip_bfloat16* __restrict__ D,
                                            __hip_bfloat16* __restrict__ out,
                                            const float* __restrict__ alpha_ptr,
                                            int alpha_recip, float alpha_c,
                                            float beta, float gamma,
                                            float* __restrict__ nrm)
{
    __shared__ __hip_bfloat16 As[128][72];   // pad +8: bank quad (4r+s)%32, <=2-way
    __shared__ __hip_bfloat16 Bs[128][72];

    const int b  = blockIdx.x;
    const int t  = blockIdx.y;
    const int ti = (t == 2) ? 1 : 0;
    const int tj = (t == 0) ? 0 : 1;
    const int tid = threadIdx.x;
    const int wv = tid >> 6, l = tid & 63;
    const int wr = wv >> 1, wc = wv & 1;
    const int lr = l & 15,  lg = l >> 4;

    const __hip_bfloat16* Ab = A  + (size_t)b * (CDIM * KT) + (size_t)ti * 128 * KT;
    const __hip_bfloat16* Bb = Bm + (size_t)b * (CDIM * KT) + (size_t)tj * 128 * KT;

    f32x4 acc[4][4];
    #pragma unroll
    for (int i = 0; i < 4; i++)
        #pragma unroll
        for (int j = 0; j < 4; j++)
            #pragma unroll
            for (int r = 0; r < 4; r++) acc[i][j][r] = 0.0f;

    #pragma unroll
    for (int k0 = 0; k0 < KT; k0 += 64) {
        const int kw   = (KT - k0 >= 64) ? 64 : (KT - k0);   // 64 or 32
        const int segs = kw >> 3;                            // 8 or 4
        __syncthreads();
        for (int u = tid; u < 128 * segs; u += 256) {
            const int row = u / segs;
            const int seg = u - row * segs;
            *reinterpret_cast<u32x4*>(&As[row][seg * 8]) =
                *reinterpret_cast<const u32x4*>(Ab + (size_t)row * KT + k0 + seg * 8);
            *reinterpret_cast<u32x4*>(&Bs[row][seg * 8]) =
                *reinterpret_cast<const u32x4*>(Bb + (size_t)row * KT + k0 + seg * 8);
        }
        __syncthreads();
        const int nks = kw >> 5;   // 2 or 1
        for (int ks = 0; ks < nks; ks++) {
            short8_t af[4], bfr[4];
            #pragma unroll
            for (int i = 0; i < 4; i++)
                af[i] = *reinterpret_cast<const short8_t*>(&As[wr * 64 + i * 16 + lr][ks * 32 + lg * 8]);
            #pragma unroll
            for (int j = 0; j < 4; j++)
                bfr[j] = *reinterpret_cast<const short8_t*>(&Bs[wc * 64 + j * 16 + lr][ks * 32 + lg * 8]);
            #pragma unroll
            for (int i = 0; i < 4; i++)
                #pragma unroll
                for (int j = 0; j < 4; j++)
                    acc[i][j] = __builtin_amdgcn_mfma_f32_16x16x32_bf16(af[i], bfr[j], acc[i][j], 0, 0, 0);
        }
    }

    float a = alpha_c;
    if (alpha_ptr) { const float tv = alpha_ptr[b]; a *= alpha_recip ? (1.0f / tv) : tv; }
    __hip_bfloat16* ob = out + (size_t)b * CC;
    const __hip_bfloat16* Db = D ? (D + (size_t)b * CC) : nullptr;
    float ns = 0.0f;
    #pragma unroll
    for (int i = 0; i < 4; i++) {
        #pragma unroll
        for (int j = 0; j < 4; j++) {
            #pragma unroll
            for (int r = 0; r < 4; r++) {
                const int grow = ti * 128 + wr * 64 + i * 16 + lg * 4 + r;
                const int gcol = tj * 128 + wc * 64 + j * 16 + lr;
                float v = a * acc[i][j][r];
                if (Db) v += beta * __bfloat162float(Db[grow * 256 + gcol]);
                if (grow == gcol) v += gamma;
                const __hip_bfloat16 hv = __float2bfloat16(v);
                ob[grow * 256 + gcol] = hv;
                if (ti != tj) ob[gcol * 256 + grow] = hv;   // exact-symmetry mirror
                if (NORM) {
                    const float fv = __bfloat162float(hv);
                    ns += ((ti != tj) ? 2.0f : 1.0f) * fv * fv;
                }
            }
        }
    }
    if (NORM) {
        #pragma unroll
        for (int o = 32; o >= 1; o >>= 1) ns += __shfl_xor(ns, o, 64);
        if (l == 0) atomicAdd(nrm + b, ns);
    }
}

// ---------------------------------------------------------------------------
// Kernel 3: projection u[b,e] = sum_k flat[b,k] * W[e,k]  (split-K, MFMA)
// grid (32 ksplits, 8 e-tiles); each of 4 waves owns K-chunk 512 -> partial
// upart[p=ks*4+wv][64][512], reduced in k_final. W converted f32->bf16 in-reg.
// ---------------------------------------------------------------------------
__global__ __launch_bounds__(256) void k_proj(const __hip_bfloat16* __restrict__ flat,
                                              const float* __restrict__ W,
                                              float* __restrict__ upart)
{
    const int ks = blockIdx.x;   // 0..31
    const int et = blockIdx.y;   // 0..7
    const int tid = threadIdx.x, wv = tid >> 6, l = tid & 63;
    const int lr = l & 15, lg = l >> 4;
    const int kbase = ks * 2048 + wv * 512;

    f32x4 acc[4][4];
    #pragma unroll
    for (int i = 0; i < 4; i++)
        #pragma unroll
        for (int j = 0; j < 4; j++)
            #pragma unroll
            for (int r = 0; r < 4; r++) acc[i][j][r] = 0.0f;

    for (int kk = 0; kk < 512; kk += 32) {
        const int k = kbase + kk + lg * 8;
        short8_t af[4];
        #pragma unroll
        for (int i = 0; i < 4; i++)
            af[i] = *reinterpret_cast<const short8_t*>(flat + (size_t)(i * 16 + lr) * CC + k);
        short8_t bfr[4];
        #pragma unroll
        for (int j = 0; j < 4; j++) {
            const f32x4* wp = reinterpret_cast<const f32x4*>(W + (size_t)(et * 64 + j * 16 + lr) * CC + k);
            const f32x4 w0 = wp[0], w1 = wp[1];
            short8_t s;
            s[0] = f2bf(w0[0]); s[1] = f2bf(w0[1]); s[2] = f2bf(w0[2]); s[3] = f2bf(w0[3]);
            s[4] = f2bf(w1[0]); s[5] = f2bf(w1[1]); s[6] = f2bf(w1[2]); s[7] = f2bf(w1[3]);
            bfr[j] = s;
        }
        #pragma unroll
        for (int i = 0; i < 4; i++)
            #pragma unroll
            for (int j = 0; j < 4; j++)
                acc[i][j] = __builtin_amdgcn_mfma_f32_16x16x32_bf16(af[i], bfr[j], acc[i][j], 0, 0, 0);
    }

    const int p = ks * 4 + wv;
    float* ub = upart + (size_t)p * (64 * EDIM);
    #pragma unroll
    for (int i = 0; i < 4; i++)
        #pragma unroll
        for (int j = 0; j < 4; j++)
            #pragma unroll
            for (int r = 0; r < 4; r++) {
                const int m = i * 16 + lg * 4 + r;
                const int e = et * 64 + j * 16 + lr;
                ub[(size_t)m * EDIM + e] = acc[i][j][r];
            }
}

// ---------------------------------------------------------------------------
// Kernel 4: reduce partials, scale by 1/||Y3||_F, +bias, BN, final L2 norm
// ---------------------------------------------------------------------------
__global__ __launch_bounds__(512) void k_final(const float* __restrict__ upart,
                                               const float* __restrict__ nrm,
                                               const float* __restrict__ bias,
                                               const float* __restrict__ gma,
                                               const float* __restrict__ bta,
                                               const float* __restrict__ mu,
                                               const float* __restrict__ var,
                                               float* __restrict__ out)
{
    const int b = blockIdx.x;
    const int e = threadIdx.x;   // 512
    float u = 0.0f;
    for (int p = 0; p < 128; p++)
        u += upart[((size_t)p * 64 + b) * EDIM + e];
    const float s = 1.0f / fmaxf(sqrtf(nrm[b]), 1e-12f);
    const float emb = s * u + bias[e];
    const float v = (emb - mu[e]) * rsqrtf(var[e] + 1e-5f) * gma[e] + bta[e];
    float sq = v * v;
    #pragma unroll
    for (int o = 32; o >= 1; o >>= 1) sq += __shfl_xor(sq, o, 64);
    __shared__ float wsum[8];
    if ((e & 63) == 0) wsum[e >> 6] = sq;
    __syncthreads();
    float tot = 0.0f;
    #pragma unroll
    for (int i = 0; i < 8; i++) tot += wsum[i];
    out[(size_t)b * EDIM + e] = v / fmaxf(sqrtf(tot), 1e-12f);
}

// ---------------------------------------------------------------------------
extern "C" void kernel_launch(void* const* d_in, const int* in_sizes, int n_in,
                              void* d_out, int out_size, void* d_ws, size_t ws_size,
                              hipStream_t stream)
{
    const float* feat = (const float*)d_in[0];
    const float* W    = (const float*)d_in[1];
    const float* bias = (const float*)d_in[2];
    const float* gma  = (const float*)d_in[3];
    const float* bta  = (const float*)d_in[4];
    const float* mu   = (const float*)d_in[5];
    const float* var  = (const float*)d_in[6];
    float* out = (float*)d_out;

    char* ws = (char*)d_ws;
    constexpr size_t XCB_BYTES = (size_t)BATCH * CDIM * MP * 2;   // 7,340,032
    constexpr size_t MATB      = (size_t)BATCH * CC * 2;          // 8,388,608
    constexpr size_t OFF_XCB   = 1024;
    constexpr size_t OFF_M     = OFF_XCB + XCB_BYTES;
    constexpr size_t OFF_UP    = OFF_M + 4 * MATB;
    constexpr size_t NEEDED    = OFF_UP + (size_t)128 * 64 * EDIM * 4;
    if (ws_size < NEEDED) return;   // ~58 MB required

    float* tr  = (float*)(ws + 0);
    float* nrm = (float*)(ws + 256);
    __hip_bfloat16* xcb = (__hip_bfloat16*)(ws + OFF_XCB);
    __hip_bfloat16* M0  = (__hip_bfloat16*)(ws + OFF_M + 0 * MATB);
    __hip_bfloat16* M1  = (__hip_bfloat16*)(ws + OFF_M + 1 * MATB);
    __hip_bfloat16* M2  = (__hip_bfloat16*)(ws + OFF_M + 2 * MATB);
    __hip_bfloat16* M3  = (__hip_bfloat16*)(ws + OFF_M + 3 * MATB);
    float* upart = (float*)(ws + OFF_UP);

    hipMemsetAsync(ws, 0, 512, stream);   // tr + nrm accumulators

    k_center<<<dim3(4096), dim3(256), 0, stream>>>(feat, xcb, tr);

    // y = (1/tr) * xc @ xc^T                                        -> M0
    k_mm<MP, false><<<dim3(64, 3), 256, 0, stream>>>(xcb, xcb, nullptr, M0, tr, 1, 1.0f, 0.0f, 0.0f, nullptr);
    // Y1 = -0.5*y@y + 1.5*y                                         -> M1
    k_mm<256, false><<<dim3(64, 3), 256, 0, stream>>>(M0, M0, M0, M1, nullptr, 0, -0.5f, 1.5f, 0.0f, nullptr);
    // T2 = 0.5*y@Y1 - 1.5*Y1 + 3I                                   -> M2
    k_mm<256, false><<<dim3(64, 3), 256, 0, stream>>>(M0, M1, M1, M2, nullptr, 0, 0.5f, -1.5f, 3.0f, nullptr);
    // Y2 = 0.5*Y1@T2                                                -> M3
    k_mm<256, false><<<dim3(64, 3), 256, 0, stream>>>(M1, M2, nullptr, M3, nullptr, 0, 0.5f, 0.0f, 0.0f, nullptr);
    // Z2 = -0.25*T2@y + 0.75*T2                                     -> M1
    k_mm<256, false><<<dim3(64, 3), 256, 0, stream>>>(M2, M0, M2, M1, nullptr, 0, -0.25f, 0.75f, 0.0f, nullptr);
    // T3 = -Z2@Y2 + 3I                                              -> M2
    k_mm<256, false><<<dim3(64, 3), 256, 0, stream>>>(M1, M3, nullptr, M2, nullptr, 0, -1.0f, 0.0f, 3.0f, nullptr);
    // Y3 = 0.5*Y2@T3  (+ Frobenius norm^2 -> nrm)                   -> M0
    k_mm<256, true ><<<dim3(64, 3), 256, 0, stream>>>(M3, M2, nullptr, M0, nullptr, 0, 0.5f, 0.0f, 0.0f, nrm);

    k_proj<<<dim3(32, 8), 256, 0, stream>>>(M0, W, upart);
    k_final<<<dim3(64), 512, 0, stream>>>(upart, nrm, bias, gma, bta, mu, var, out);
}

// Round 2
// 193.140 us; speedup vs baseline: 1.6321x; 1.6321x over previous
//
#include <hip/hip_runtime.h>
#include <hip/hip_bf16.h>

#define BATCH 64
#define CDIM  256
#define MHW   196
#define MP    224      // padded K for covariance (multiple of 32)
#define EDIM  512
#define CC    65536    // CDIM*CDIM

typedef __attribute__((ext_vector_type(8))) short short8_t;   // 8 x bf16 MFMA frag
typedef __attribute__((ext_vector_type(4))) float f32x4;
typedef __attribute__((ext_vector_type(4))) unsigned int u32x4;

static __device__ __forceinline__ short f2bf(float f) {
    __hip_bfloat16 h = __float2bfloat16(f);
    return (short)__builtin_bit_cast(unsigned short, h);
}

// ---------------------------------------------------------------------------
// Kernel 1: per-(b,c) row centering, bf16 cast (padded to MP).
// Writes per-row sum-of-squares to rowsq[row] (NO atomics — round-1 rocprof
// showed 16384 contended atomicAdds onto 64 addresses cost ~120us).
// ---------------------------------------------------------------------------
__global__ __launch_bounds__(256) void k_center(const float* __restrict__ feat,
                                                __hip_bfloat16* __restrict__ xcb,
                                                float* __restrict__ rowsq)
{
    const int row = blockIdx.x * 4 + (threadIdx.x >> 6);   // [0, 64*256)
    const int l = threadIdx.x & 63;
    const float* src = feat + (size_t)row * MHW;
    float v0 = src[l];
    float v1 = src[l + 64];
    float v2 = src[l + 128];
    float v3 = (l + 192 < MHW) ? src[l + 192] : 0.0f;
    float s = v0 + v1 + v2 + v3;
    #pragma unroll
    for (int o = 32; o >= 1; o >>= 1) s += __shfl_xor(s, o, 64);
    const float mean = s * (1.0f / MHW);
    v0 -= mean; v1 -= mean; v2 -= mean;
    v3 = (l + 192 < MHW) ? (v3 - mean) : 0.0f;
    float sq = v0*v0 + v1*v1 + v2*v2 + v3*v3;
    #pragma unroll
    for (int o = 32; o >= 1; o >>= 1) sq += __shfl_xor(sq, o, 64);
    if (l == 0) rowsq[row] = sq;
    __hip_bfloat16* dst = xcb + (size_t)row * MP;
    dst[l]       = __float2bfloat16(v0);
    dst[l + 64]  = __float2bfloat16(v1);
    dst[l + 128] = __float2bfloat16(v2);
    if (l + 192 < MP) dst[l + 192] = __float2bfloat16(v3);   // includes zero pad
}

// ---------------------------------------------------------------------------
// Kernel 1b: tr[b] = sum over 256 rows of rowsq  (tiny, no atomics)
// ---------------------------------------------------------------------------
__global__ __launch_bounds__(256) void k_trace(const float* __restrict__ rowsq,
                                               float* __restrict__ tr)
{
    const int b = blockIdx.x;
    float v = rowsq[b * 256 + threadIdx.x];
    #pragma unroll
    for (int o = 32; o >= 1; o >>= 1) v += __shfl_xor(v, o, 64);
    __shared__ float red[4];
    if ((threadIdx.x & 63) == 0) red[threadIdx.x >> 6] = v;
    __syncthreads();
    if (threadIdx.x == 0) tr[b] = red[0] + red[1] + red[2] + red[3];
}

// ---------------------------------------------------------------------------
// Kernel 2: batched symmetric matmul tile kernel.
// out = a*(A@B) + beta*D + gamma*I   per batch, 256x256, bf16 in/out, f32 acc.
// a = alpha_c * (alpha_ptr ? (recip ? 1/alpha_ptr[b] : alpha_ptr[b]) : 1)
// B is read via its ROWS (valid: every B operand is exactly symmetric in
// storage thanks to mirrored writes). Upper-triangle tiles only (t=0,1,2 ->
// (0,0),(0,1),(1,1)); off-diagonal tile mirror-writes.
// KT: K extent AND row stride of A/B (224 for covariance input, else 256).
// NORM: write this block's Frobenius-norm^2 partial to nrm[b*3+t].
// ---------------------------------------------------------------------------
template<int KT, bool NORM>
__global__ __launch_bounds__(256) void k_mm(const __hip_bfloat16* __restrict__ A,
                                            const __hip_bfloat16* __restrict__ Bm,
                                            const __hip_bfloat16* __restrict__ D,
                                            __hip_bfloat16* __restrict__ out,
                                            const float* __restrict__ alpha_ptr,
                                            int alpha_recip, float alpha_c,
                                            float beta, float gamma,
                                            float* __restrict__ nrm)
{
    __shared__ __hip_bfloat16 As[128][72];   // pad +8: bank quad (4r+s)%32, <=2-way
    __shared__ __hip_bfloat16 Bs[128][72];

    const int b  = blockIdx.x;
    const int t  = blockIdx.y;
    const int ti = (t == 2) ? 1 : 0;
    const int tj = (t == 0) ? 0 : 1;
    const int tid = threadIdx.x;
    const int wv = tid >> 6, l = tid & 63;
    const int wr = wv >> 1, wc = wv & 1;
    const int lr = l & 15,  lg = l >> 4;

    const __hip_bfloat16* Ab = A  + (size_t)b * (CDIM * KT) + (size_t)ti * 128 * KT;
    const __hip_bfloat16* Bb = Bm + (size_t)b * (CDIM * KT) + (size_t)tj * 128 * KT;

    f32x4 acc[4][4];
    #pragma unroll
    for (int i = 0; i < 4; i++)
        #pragma unroll
        for (int j = 0; j < 4; j++)
            #pragma unroll
            for (int r = 0; r < 4; r++) acc[i][j][r] = 0.0f;

    #pragma unroll
    for (int k0 = 0; k0 < KT; k0 += 64) {
        const int kw   = (KT - k0 >= 64) ? 64 : (KT - k0);   // 64 or 32
        const int segs = kw >> 3;                            // 8 or 4
        __syncthreads();
        for (int u = tid; u < 128 * segs; u += 256) {
            const int row = u / segs;
            const int seg = u - row * segs;
            *reinterpret_cast<u32x4*>(&As[row][seg * 8]) =
                *reinterpret_cast<const u32x4*>(Ab + (size_t)row * KT + k0 + seg * 8);
            *reinterpret_cast<u32x4*>(&Bs[row][seg * 8]) =
                *reinterpret_cast<const u32x4*>(Bb + (size_t)row * KT + k0 + seg * 8);
        }
        __syncthreads();
        const int nks = kw >> 5;   // 2 or 1
        for (int ks = 0; ks < nks; ks++) {
            short8_t af[4], bfr[4];
            #pragma unroll
            for (int i = 0; i < 4; i++)
                af[i] = *reinterpret_cast<const short8_t*>(&As[wr * 64 + i * 16 + lr][ks * 32 + lg * 8]);
            #pragma unroll
            for (int j = 0; j < 4; j++)
                bfr[j] = *reinterpret_cast<const short8_t*>(&Bs[wc * 64 + j * 16 + lr][ks * 32 + lg * 8]);
            #pragma unroll
            for (int i = 0; i < 4; i++)
                #pragma unroll
                for (int j = 0; j < 4; j++)
                    acc[i][j] = __builtin_amdgcn_mfma_f32_16x16x32_bf16(af[i], bfr[j], acc[i][j], 0, 0, 0);
        }
    }

    float a = alpha_c;
    if (alpha_ptr) { const float tv = alpha_ptr[b]; a *= alpha_recip ? (1.0f / tv) : tv; }
    __hip_bfloat16* ob = out + (size_t)b * CC;
    const __hip_bfloat16* Db = D ? (D + (size_t)b * CC) : nullptr;
    float ns = 0.0f;
    #pragma unroll
    for (int i = 0; i < 4; i++) {
        #pragma unroll
        for (int j = 0; j < 4; j++) {
            #pragma unroll
            for (int r = 0; r < 4; r++) {
                const int grow = ti * 128 + wr * 64 + i * 16 + lg * 4 + r;
                const int gcol = tj * 128 + wc * 64 + j * 16 + lr;
                float v = a * acc[i][j][r];
                if (Db) v += beta * __bfloat162float(Db[grow * 256 + gcol]);
                if (grow == gcol) v += gamma;
                const __hip_bfloat16 hv = __float2bfloat16(v);
                ob[grow * 256 + gcol] = hv;
                if (ti != tj) ob[gcol * 256 + grow] = hv;   // exact-symmetry mirror
                if (NORM) {
                    const float fv = __bfloat162float(hv);
                    ns += ((ti != tj) ? 2.0f : 1.0f) * fv * fv;
                }
            }
        }
    }
    if constexpr (NORM) {
        #pragma unroll
        for (int o = 32; o >= 1; o >>= 1) ns += __shfl_xor(ns, o, 64);
        __shared__ float red[4];
        if (l == 0) red[wv] = ns;
        __syncthreads();
        if (tid == 0) nrm[b * 3 + t] = red[0] + red[1] + red[2] + red[3];
    }
}

// ---------------------------------------------------------------------------
// Kernel 3: projection u[b,e] = sum_k flat[b,k] * W[e,k]  (split-K, MFMA)
// grid (32 ksplits, 8 e-tiles); each of 4 waves owns K-chunk 512 -> partial
// upart[p=ks*4+wv][64][512], reduced in k_final. W converted f32->bf16 in-reg.
// ---------------------------------------------------------------------------
__global__ __launch_bounds__(256) void k_proj(const __hip_bfloat16* __restrict__ flat,
                                              const float* __restrict__ W,
                                              float* __restrict__ upart)
{
    const int ks = blockIdx.x;   // 0..31
    const int et = blockIdx.y;   // 0..7
    const int tid = threadIdx.x, wv = tid >> 6, l = tid & 63;
    const int lr = l & 15, lg = l >> 4;
    const int kbase = ks * 2048 + wv * 512;

    f32x4 acc[4][4];
    #pragma unroll
    for (int i = 0; i < 4; i++)
        #pragma unroll
        for (int j = 0; j < 4; j++)
            #pragma unroll
            for (int r = 0; r < 4; r++) acc[i][j][r] = 0.0f;

    for (int kk = 0; kk < 512; kk += 32) {
        const int k = kbase + kk + lg * 8;
        short8_t af[4];
        #pragma unroll
        for (int i = 0; i < 4; i++)
            af[i] = *reinterpret_cast<const short8_t*>(flat + (size_t)(i * 16 + lr) * CC + k);
        short8_t bfr[4];
        #pragma unroll
        for (int j = 0; j < 4; j++) {
            const f32x4* wp = reinterpret_cast<const f32x4*>(W + (size_t)(et * 64 + j * 16 + lr) * CC + k);
            const f32x4 w0 = wp[0], w1 = wp[1];
            short8_t s;
            s[0] = f2bf(w0[0]); s[1] = f2bf(w0[1]); s[2] = f2bf(w0[2]); s[3] = f2bf(w0[3]);
            s[4] = f2bf(w1[0]); s[5] = f2bf(w1[1]); s[6] = f2bf(w1[2]); s[7] = f2bf(w1[3]);
            bfr[j] = s;
        }
        #pragma unroll
        for (int i = 0; i < 4; i++)
            #pragma unroll
            for (int j = 0; j < 4; j++)
                acc[i][j] = __builtin_amdgcn_mfma_f32_16x16x32_bf16(af[i], bfr[j], acc[i][j], 0, 0, 0);
    }

    const int p = ks * 4 + wv;
    float* ub = upart + (size_t)p * (64 * EDIM);
    #pragma unroll
    for (int i = 0; i < 4; i++)
        #pragma unroll
        for (int j = 0; j < 4; j++)
            #pragma unroll
            for (int r = 0; r < 4; r++) {
                const int m = i * 16 + lg * 4 + r;
                const int e = et * 64 + j * 16 + lr;
                ub[(size_t)m * EDIM + e] = acc[i][j][r];
            }
}

// ---------------------------------------------------------------------------
// Kernel 4: reduce partials, scale by 1/||Y3||_F, +bias, BN, final L2 norm
// ---------------------------------------------------------------------------
__global__ __launch_bounds__(512) void k_final(const float* __restrict__ upart,
                                               const float* __restrict__ nrmp,
                                               const float* __restrict__ bias,
                                               const float* __restrict__ gma,
                                               const float* __restrict__ bta,
                                               const float* __restrict__ mu,
                                               const float* __restrict__ var,
                                               float* __restrict__ out)
{
    const int b = blockIdx.x;
    const int e = threadIdx.x;   // 512
    float u = 0.0f;
    for (int p = 0; p < 128; p++)
        u += upart[((size_t)p * 64 + b) * EDIM + e];
    const float fro = nrmp[b * 3 + 0] + nrmp[b * 3 + 1] + nrmp[b * 3 + 2];
    const float s = 1.0f / fmaxf(sqrtf(fro), 1e-12f);
    const float emb = s * u + bias[e];
    const float v = (emb - mu[e]) * rsqrtf(var[e] + 1e-5f) * gma[e] + bta[e];
    float sq = v * v;
    #pragma unroll
    for (int o = 32; o >= 1; o >>= 1) sq += __shfl_xor(sq, o, 64);
    __shared__ float wsum[8];
    if ((e & 63) == 0) wsum[e >> 6] = sq;
    __syncthreads();
    float tot = 0.0f;
    #pragma unroll
    for (int i = 0; i < 8; i++) tot += wsum[i];
    out[(size_t)b * EDIM + e] = v / fmaxf(sqrtf(tot), 1e-12f);
}

// ---------------------------------------------------------------------------
extern "C" void kernel_launch(void* const* d_in, const int* in_sizes, int n_in,
                              void* d_out, int out_size, void* d_ws, size_t ws_size,
                              hipStream_t stream)
{
    const float* feat = (const float*)d_in[0];
    const float* W    = (const float*)d_in[1];
    const float* bias = (const float*)d_in[2];
    const float* gma  = (const float*)d_in[3];
    const float* bta  = (const float*)d_in[4];
    const float* mu   = (const float*)d_in[5];
    const float* var  = (const float*)d_in[6];
    float* out = (float*)d_out;

    char* ws = (char*)d_ws;
    constexpr size_t XCB_BYTES = (size_t)BATCH * CDIM * MP * 2;   // 7,340,032
    constexpr size_t MATB      = (size_t)BATCH * CC * 2;          // 8,388,608
    constexpr size_t OFF_ROWSQ = 4096;
    constexpr size_t OFF_XCB   = OFF_ROWSQ + (size_t)BATCH * CDIM * 4;  // +64KB
    constexpr size_t OFF_M     = OFF_XCB + XCB_BYTES;
    constexpr size_t OFF_UP    = OFF_M + 4 * MATB;
    constexpr size_t NEEDED    = OFF_UP + (size_t)128 * 64 * EDIM * 4;
    if (ws_size < NEEDED) return;   // ~58 MB required

    float* tr    = (float*)(ws + 0);
    float* nrmp  = (float*)(ws + 1024);          // 192 floats
    float* rowsq = (float*)(ws + OFF_ROWSQ);     // 16384 floats
    __hip_bfloat16* xcb = (__hip_bfloat16*)(ws + OFF_XCB);
    __hip_bfloat16* M0  = (__hip_bfloat16*)(ws + OFF_M + 0 * MATB);
    __hip_bfloat16* M1  = (__hip_bfloat16*)(ws + OFF_M + 1 * MATB);
    __hip_bfloat16* M2  = (__hip_bfloat16*)(ws + OFF_M + 2 * MATB);
    __hip_bfloat16* M3  = (__hip_bfloat16*)(ws + OFF_M + 3 * MATB);
    float* upart = (float*)(ws + OFF_UP);

    k_center<<<dim3(4096), dim3(256), 0, stream>>>(feat, xcb, rowsq);
    k_trace<<<dim3(64), dim3(256), 0, stream>>>(rowsq, tr);

    // y = (1/tr) * xc @ xc^T                                        -> M0
    k_mm<MP, false><<<dim3(64, 3), 256, 0, stream>>>(xcb, xcb, nullptr, M0, tr, 1, 1.0f, 0.0f, 0.0f, nullptr);
    // Y1 = -0.5*y@y + 1.5*y                                         -> M1
    k_mm<256, false><<<dim3(64, 3), 256, 0, stream>>>(M0, M0, M0, M1, nullptr, 0, -0.5f, 1.5f, 0.0f, nullptr);
    // T2 = 0.5*y@Y1 - 1.5*Y1 + 3I                                   -> M2
    k_mm<256, false><<<dim3(64, 3), 256, 0, stream>>>(M0, M1, M1, M2, nullptr, 0, 0.5f, -1.5f, 3.0f, nullptr);
    // Y2 = 0.5*Y1@T2                                                -> M3
    k_mm<256, false><<<dim3(64, 3), 256, 0, stream>>>(M1, M2, nullptr, M3, nullptr, 0, 0.5f, 0.0f, 0.0f, nullptr);
    // Z2 = -0.25*T2@y + 0.75*T2                                     -> M1
    k_mm<256, false><<<dim3(64, 3), 256, 0, stream>>>(M2, M0, M2, M1, nullptr, 0, -0.25f, 0.75f, 0.0f, nullptr);
    // T3 = -Z2@Y2 + 3I                                              -> M2
    k_mm<256, false><<<dim3(64, 3), 256, 0, stream>>>(M1, M3, nullptr, M2, nullptr, 0, -1.0f, 0.0f, 3.0f, nullptr);
    // Y3 = 0.5*Y2@T3  (+ Frobenius norm^2 partials -> nrmp)         -> M0
    k_mm<256, true ><<<dim3(64, 3), 256, 0, stream>>>(M3, M2, nullptr, M0, nullptr, 0, 0.5f, 0.0f, 0.0f, nrmp);

    k_proj<<<dim3(32, 8), 256, 0, stream>>>(M0, W, upart);
    k_final<<<dim3(64), 512, 0, stream>>>(upart, nrmp, bias, gma, bta, mu, var, out);
}

// Round 3
// 133.131 us; speedup vs baseline: 2.3677x; 1.4508x over previous
//
#include <hip/hip_runtime.h>
#include <hip/hip_bf16.h>

#define BATCH 64
#define CDIM  256
#define MHW   196
#define MP    224      // padded K for covariance (multiple of 32)
#define EDIM  512
#define CC    65536    // CDIM*CDIM
#define NTRI  10       // upper-triangle 64x64 tiles of a 256x256 matrix

typedef __attribute__((ext_vector_type(8))) short short8_t;   // 8 x bf16 MFMA frag
typedef __attribute__((ext_vector_type(4))) float f32x4;
typedef __attribute__((ext_vector_type(4))) unsigned int u32x4;

static __device__ __forceinline__ short f2bf(float f) {
    __hip_bfloat16 h = __float2bfloat16(f);
    return (short)__builtin_bit_cast(unsigned short, h);
}

struct MMOp {
    const __hip_bfloat16* A;
    const __hip_bfloat16* B;
    const __hip_bfloat16* D;
    __hip_bfloat16*       out;
    const float*          alpha_ptr;   // mode!=0: rowsq base, alpha = alpha_c / sum_256(rowsq[b])
    int                   alpha_mode;
    float                 alpha_c, beta, gamma;
    float*                nrm;
};

// ---------------------------------------------------------------------------
// Kernel 1: per-(b,c) row centering, bf16 cast (padded to MP).
// Per-row sum-of-squares -> rowsq[row] (no atomics).
// ---------------------------------------------------------------------------
__global__ __launch_bounds__(256) void k_center(const float* __restrict__ feat,
                                                __hip_bfloat16* __restrict__ xcb,
                                                float* __restrict__ rowsq)
{
    const int row = blockIdx.x * 4 + (threadIdx.x >> 6);   // [0, 64*256)
    const int l = threadIdx.x & 63;
    const float* src = feat + (size_t)row * MHW;
    float v0 = src[l];
    float v1 = src[l + 64];
    float v2 = src[l + 128];
    float v3 = (l + 192 < MHW) ? src[l + 192] : 0.0f;
    float s = v0 + v1 + v2 + v3;
    #pragma unroll
    for (int o = 32; o >= 1; o >>= 1) s += __shfl_xor(s, o, 64);
    const float mean = s * (1.0f / MHW);
    v0 -= mean; v1 -= mean; v2 -= mean;
    v3 = (l + 192 < MHW) ? (v3 - mean) : 0.0f;
    float sq = v0*v0 + v1*v1 + v2*v2 + v3*v3;
    #pragma unroll
    for (int o = 32; o >= 1; o >>= 1) sq += __shfl_xor(sq, o, 64);
    if (l == 0) rowsq[row] = sq;
    __hip_bfloat16* dst = xcb + (size_t)row * MP;
    dst[l]       = __float2bfloat16(v0);
    dst[l + 64]  = __float2bfloat16(v1);
    dst[l + 128] = __float2bfloat16(v2);
    if (l + 192 < MP) dst[l + 192] = __float2bfloat16(v3);   // includes zero pad
}

// ---------------------------------------------------------------------------
// Kernel 2: batched symmetric matmul, 64x64 tiles over the upper triangle.
// out = a*(A@B^T) + beta*D + gamma*I ; B stored symmetric so A@B^T == A@B.
// grid = (BATCH*NTRI, nops); blockIdx.y selects op0/op1 (merged independent
// matmuls). 4 waves in 2x2, each 32x32 output. Mirror-write keeps storage
// exactly symmetric. alpha_mode: block-local reduce of rowsq -> a=alpha_c/tr.
// ---------------------------------------------------------------------------
template<int KT, bool NORM>
__global__ __launch_bounds__(256) void k_mm(MMOp op0, MMOp op1)
{
    const MMOp& op = (blockIdx.y == 0) ? op0 : op1;

    __shared__ __hip_bfloat16 As[64][72];
    __shared__ __hip_bfloat16 Bs[64][72];
    __shared__ float red[4];
    __shared__ float s_alpha;

    const int b = blockIdx.x / NTRI;
    const int t = blockIdx.x - b * NTRI;
    int ti, tj;
    if (t < 4)      { ti = 0; tj = t; }
    else if (t < 7) { ti = 1; tj = t - 3; }
    else if (t < 9) { ti = 2; tj = t - 5; }
    else            { ti = 3; tj = 3; }

    const int tid = threadIdx.x;
    const int wv = tid >> 6, l = tid & 63;
    const int wr = wv >> 1, wc = wv & 1;
    const int lr = l & 15,  lg = l >> 4;

    if (op.alpha_mode) {
        float v = op.alpha_ptr[b * 256 + tid];
        #pragma unroll
        for (int o = 32; o >= 1; o >>= 1) v += __shfl_xor(v, o, 64);
        if (l == 0) red[wv] = v;
        __syncthreads();
        if (tid == 0) s_alpha = op.alpha_c / (red[0] + red[1] + red[2] + red[3]);
    } else if (tid == 0) {
        s_alpha = op.alpha_c;
    }

    const __hip_bfloat16* Ab = op.A + (size_t)b * (CDIM * KT) + (size_t)ti * 64 * KT;
    const __hip_bfloat16* Bb = op.B + (size_t)b * (CDIM * KT) + (size_t)tj * 64 * KT;

    f32x4 acc[2][2];
    #pragma unroll
    for (int i = 0; i < 2; i++)
        #pragma unroll
        for (int j = 0; j < 2; j++)
            #pragma unroll
            for (int r = 0; r < 4; r++) acc[i][j][r] = 0.0f;

    #pragma unroll
    for (int k0 = 0; k0 < KT; k0 += 64) {
        const int kw   = (KT - k0 >= 64) ? 64 : (KT - k0);   // 64 or 32
        const int segs = kw >> 3;                            // 8 or 4
        __syncthreads();
        for (int u = tid; u < 64 * segs; u += 256) {
            const int row = u / segs;
            const int seg = u - row * segs;
            *reinterpret_cast<u32x4*>(&As[row][seg * 8]) =
                *reinterpret_cast<const u32x4*>(Ab + (size_t)row * KT + k0 + seg * 8);
            *reinterpret_cast<u32x4*>(&Bs[row][seg * 8]) =
                *reinterpret_cast<const u32x4*>(Bb + (size_t)row * KT + k0 + seg * 8);
        }
        __syncthreads();
        const int nks = kw >> 5;   // 2 or 1
        for (int ks = 0; ks < nks; ks++) {
            short8_t af[2], bfr[2];
            #pragma unroll
            for (int i = 0; i < 2; i++)
                af[i] = *reinterpret_cast<const short8_t*>(&As[wr * 32 + i * 16 + lr][ks * 32 + lg * 8]);
            #pragma unroll
            for (int j = 0; j < 2; j++)
                bfr[j] = *reinterpret_cast<const short8_t*>(&Bs[wc * 32 + j * 16 + lr][ks * 32 + lg * 8]);
            #pragma unroll
            for (int i = 0; i < 2; i++)
                #pragma unroll
                for (int j = 0; j < 2; j++)
                    acc[i][j] = __builtin_amdgcn_mfma_f32_16x16x32_bf16(af[i], bfr[j], acc[i][j], 0, 0, 0);
        }
    }

    const float a = s_alpha;
    __hip_bfloat16* ob = op.out + (size_t)b * CC;
    const __hip_bfloat16* Db = op.D ? (op.D + (size_t)b * CC) : nullptr;
    float ns = 0.0f;
    #pragma unroll
    for (int i = 0; i < 2; i++) {
        #pragma unroll
        for (int j = 0; j < 2; j++) {
            #pragma unroll
            for (int r = 0; r < 4; r++) {
                const int grow = ti * 64 + wr * 32 + i * 16 + lg * 4 + r;
                const int gcol = tj * 64 + wc * 32 + j * 16 + lr;
                float v = a * acc[i][j][r];
                if (Db) v += op.beta * __bfloat162float(Db[grow * 256 + gcol]);
                if (grow == gcol) v += op.gamma;
                const __hip_bfloat16 hv = __float2bfloat16(v);
                ob[grow * 256 + gcol] = hv;
                if (ti != tj) ob[gcol * 256 + grow] = hv;   // exact-symmetry mirror
                if (NORM) {
                    const float fv = __bfloat162float(hv);
                    ns += ((ti != tj) ? 2.0f : 1.0f) * fv * fv;
                }
            }
        }
    }
    if constexpr (NORM) {
        #pragma unroll
        for (int o = 32; o >= 1; o >>= 1) ns += __shfl_xor(ns, o, 64);
        __syncthreads();
        if (l == 0) red[wv] = ns;
        __syncthreads();
        if (tid == 0) op.nrm[b * NTRI + t] = red[0] + red[1] + red[2] + red[3];
    }
}

// ---------------------------------------------------------------------------
// Kernel 3: projection u[b,e] = sum_k flat[b,k] * W[e,k]  (split-K, MFMA)
// grid (32 ksplits, 8 e-tiles); the 4 waves of a block split the block's
// 2048-wide K chunk and are reduced through LDS -> upart[32][64][512].
// W converted f32->bf16 in-register.
// ---------------------------------------------------------------------------
__global__ __launch_bounds__(256) void k_proj(const __hip_bfloat16* __restrict__ flat,
                                              const float* __restrict__ W,
                                              float* __restrict__ upart)
{
    const int ks = blockIdx.x;   // 0..31
    const int et = blockIdx.y;   // 0..7
    const int tid = threadIdx.x, wv = tid >> 6, l = tid & 63;
    const int lr = l & 15, lg = l >> 4;
    const int kbase = ks * 2048 + wv * 512;

    f32x4 acc[4][4];
    #pragma unroll
    for (int i = 0; i < 4; i++)
        #pragma unroll
        for (int j = 0; j < 4; j++)
            #pragma unroll
            for (int r = 0; r < 4; r++) acc[i][j][r] = 0.0f;

    for (int kk = 0; kk < 512; kk += 32) {
        const int k = kbase + kk + lg * 8;
        short8_t af[4];
        #pragma unroll
        for (int i = 0; i < 4; i++)
            af[i] = *reinterpret_cast<const short8_t*>(flat + (size_t)(i * 16 + lr) * CC + k);
        short8_t bfr[4];
        #pragma unroll
        for (int j = 0; j < 4; j++) {
            const f32x4* wp = reinterpret_cast<const f32x4*>(W + (size_t)(et * 64 + j * 16 + lr) * CC + k);
            const f32x4 w0 = wp[0], w1 = wp[1];
            short8_t s;
            s[0] = f2bf(w0[0]); s[1] = f2bf(w0[1]); s[2] = f2bf(w0[2]); s[3] = f2bf(w0[3]);
            s[4] = f2bf(w1[0]); s[5] = f2bf(w1[1]); s[6] = f2bf(w1[2]); s[7] = f2bf(w1[3]);
            bfr[j] = s;
        }
        #pragma unroll
        for (int i = 0; i < 4; i++)
            #pragma unroll
            for (int j = 0; j < 4; j++)
                acc[i][j] = __builtin_amdgcn_mfma_f32_16x16x32_bf16(af[i], bfr[j], acc[i][j], 0, 0, 0);
    }

    // cross-wave K reduction: (w0+w2) and (w1+w3) planes in LDS, final sum on store
    __shared__ float racc[2][64][65];
    if (wv >= 2) {
        #pragma unroll
        for (int i = 0; i < 4; i++)
            #pragma unroll
            for (int j = 0; j < 4; j++)
                #pragma unroll
                for (int r = 0; r < 4; r++)
                    racc[wv - 2][i * 16 + lg * 4 + r][j * 16 + lr] = acc[i][j][r];
    }
    __syncthreads();
    if (wv < 2) {
        #pragma unroll
        for (int i = 0; i < 4; i++)
            #pragma unroll
            for (int j = 0; j < 4; j++)
                #pragma unroll
                for (int r = 0; r < 4; r++)
                    racc[wv][i * 16 + lg * 4 + r][j * 16 + lr] += acc[i][j][r];
    }
    __syncthreads();
    float* ub = upart + (size_t)ks * (64 * EDIM);
    #pragma unroll
    for (int q = 0; q < 16; q++) {
        const int idx = q * 256 + tid;
        const int x = idx >> 6, y = idx & 63;
        ub[(size_t)x * EDIM + et * 64 + y] = racc[0][x][y] + racc[1][x][y];
    }
}

// ---------------------------------------------------------------------------
// Kernel 4: reduce partials, scale by 1/||Y3||_F, +bias, BN, final L2 norm
// ---------------------------------------------------------------------------
__global__ __launch_bounds__(512) void k_final(const float* __restrict__ upart,
                                               const float* __restrict__ nrmp,
                                               const float* __restrict__ bias,
                                               const float* __restrict__ gma,
                                               const float* __restrict__ bta,
                                               const float* __restrict__ mu,
                                               const float* __restrict__ var,
                                               float* __restrict__ out)
{
    const int b = blockIdx.x;
    const int e = threadIdx.x;   // 512
    float u = 0.0f;
    for (int p = 0; p < 32; p++)
        u += upart[((size_t)p * 64 + b) * EDIM + e];
    float fro = 0.0f;
    #pragma unroll
    for (int q = 0; q < NTRI; q++) fro += nrmp[b * NTRI + q];
    const float s = 1.0f / fmaxf(sqrtf(fro), 1e-12f);
    const float emb = s * u + bias[e];
    const float v = (emb - mu[e]) * rsqrtf(var[e] + 1e-5f) * gma[e] + bta[e];
    float sq = v * v;
    #pragma unroll
    for (int o = 32; o >= 1; o >>= 1) sq += __shfl_xor(sq, o, 64);
    __shared__ float wsum[8];
    if ((e & 63) == 0) wsum[e >> 6] = sq;
    __syncthreads();
    float tot = 0.0f;
    #pragma unroll
    for (int i = 0; i < 8; i++) tot += wsum[i];
    out[(size_t)b * EDIM + e] = v / fmaxf(sqrtf(tot), 1e-12f);
}

// ---------------------------------------------------------------------------
extern "C" void kernel_launch(void* const* d_in, const int* in_sizes, int n_in,
                              void* d_out, int out_size, void* d_ws, size_t ws_size,
                              hipStream_t stream)
{
    const float* feat = (const float*)d_in[0];
    const float* W    = (const float*)d_in[1];
    const float* bias = (const float*)d_in[2];
    const float* gma  = (const float*)d_in[3];
    const float* bta  = (const float*)d_in[4];
    const float* mu   = (const float*)d_in[5];
    const float* var  = (const float*)d_in[6];
    float* out = (float*)d_out;

    char* ws = (char*)d_ws;
    constexpr size_t XCB_BYTES = (size_t)BATCH * CDIM * MP * 2;   // 7,340,032
    constexpr size_t MATB      = (size_t)BATCH * CC * 2;          // 8,388,608
    constexpr size_t OFF_ROWSQ = 4096;
    constexpr size_t OFF_XCB   = OFF_ROWSQ + (size_t)BATCH * CDIM * 4;  // +64KB
    constexpr size_t OFF_M     = OFF_XCB + XCB_BYTES;
    constexpr size_t OFF_UP    = OFF_M + 5 * MATB;
    constexpr size_t NEEDED    = OFF_UP + (size_t)32 * 64 * EDIM * 4;
    if (ws_size < NEEDED) return;   // ~54 MB required

    float* nrmp  = (float*)(ws + 1024);          // 640 floats
    float* rowsq = (float*)(ws + OFF_ROWSQ);     // 16384 floats
    __hip_bfloat16* xcb = (__hip_bfloat16*)(ws + OFF_XCB);
    __hip_bfloat16* M0  = (__hip_bfloat16*)(ws + OFF_M + 0 * MATB);
    __hip_bfloat16* M1  = (__hip_bfloat16*)(ws + OFF_M + 1 * MATB);
    __hip_bfloat16* M2  = (__hip_bfloat16*)(ws + OFF_M + 2 * MATB);
    __hip_bfloat16* M3  = (__hip_bfloat16*)(ws + OFF_M + 3 * MATB);
    __hip_bfloat16* M4  = (__hip_bfloat16*)(ws + OFF_M + 4 * MATB);
    float* upart = (float*)(ws + OFF_UP);

    k_center<<<dim3(4096), dim3(256), 0, stream>>>(feat, xcb, rowsq);

    const dim3 g1(BATCH * NTRI, 1), g2(BATCH * NTRI, 2), blk(256);
    MMOp nop = {};

    // y  = (1/tr) * xc @ xc^T                          -> M0
    MMOp cov = {xcb, xcb, nullptr, M0, rowsq, 1, 1.0f, 0.0f, 0.0f, nullptr};
    k_mm<MP, false><<<g1, blk, 0, stream>>>(cov, nop);
    // Y1 = -0.5*y@y + 1.5*y                            -> M1
    MMOp y1 = {M0, M0, M0, M1, nullptr, 0, -0.5f, 1.5f, 0.0f, nullptr};
    k_mm<256, false><<<g1, blk, 0, stream>>>(y1, nop);
    // T2 = 0.5*y@Y1 - 1.5*Y1 + 3I                      -> M2
    MMOp t2 = {M0, M1, M1, M2, nullptr, 0, 0.5f, -1.5f, 3.0f, nullptr};
    k_mm<256, false><<<g1, blk, 0, stream>>>(t2, nop);
    // Y2 = 0.5*Y1@T2 -> M3   ||   Z2 = -0.25*T2@y + 0.75*T2 -> M4   (merged)
    MMOp y2 = {M1, M2, nullptr, M3, nullptr, 0, 0.5f, 0.0f, 0.0f, nullptr};
    MMOp z2 = {M2, M0, M2, M4, nullptr, 0, -0.25f, 0.75f, 0.0f, nullptr};
    k_mm<256, false><<<g2, blk, 0, stream>>>(y2, z2);
    // T3 = -Z2@Y2 + 3I                                 -> M1
    MMOp t3 = {M4, M3, nullptr, M1, nullptr, 0, -1.0f, 0.0f, 3.0f, nullptr};
    k_mm<256, false><<<g1, blk, 0, stream>>>(t3, nop);
    // Y3 = 0.5*Y2@T3  (+ Frobenius norm^2 partials)    -> M2
    MMOp y3 = {M3, M1, nullptr, M2, nullptr, 0, 0.5f, 0.0f, 0.0f, nrmp};
    k_mm<256, true ><<<g1, blk, 0, stream>>>(y3, nop);

    k_proj<<<dim3(32, 8), blk, 0, stream>>>(M2, W, upart);
    k_final<<<dim3(64), 512, 0, stream>>>(upart, nrmp, bias, gma, bta, mu, var, out);
}